// Round 1
// baseline (1522.613 us; speedup 1.0000x reference)
//
#include <hip/hip_runtime.h>
#include <math.h>

#define N_NODES 100000
#define N_EDGES 1600000
#define HID 64

// ---------------- degree / normalization ----------------

__global__ void count_deg_kernel(const int* __restrict__ dst, int* __restrict__ deg) {
    int e = blockIdx.x * blockDim.x + threadIdx.x;
    if (e < N_EDGES) atomicAdd(&deg[dst[e]], 1);
}

__global__ void dinv_kernel(const int* __restrict__ deg, float* __restrict__ dinv) {
    int n = blockIdx.x * blockDim.x + threadIdx.x;
    if (n < N_NODES) dinv[n] = rsqrtf(1.0f + (float)deg[n]);
}

// ---------------- layer 1: g = dinv * (x @ W1); h = g (self-loop seed) ----------------

__global__ void layer1_kernel(const float* __restrict__ x, const float* __restrict__ W1,
                              const float* __restrict__ dinv,
                              float* __restrict__ g, float* __restrict__ h) {
    int idx = blockIdx.x * blockDim.x + threadIdx.x;
    if (idx >= N_NODES * HID) return;
    int n = idx >> 6, c = idx & 63;
    float x0 = x[n * 3 + 0], x1 = x[n * 3 + 1], x2 = x[n * 3 + 2];
    float v = x0 * W1[0 * HID + c] + x1 * W1[1 * HID + c] + x2 * W1[2 * HID + c];
    v *= dinv[n];
    g[idx] = v;
    h[idx] = v;
}

// ---------------- edge scatter: h[dst] += g[src] ----------------
// idx laid out so one 64-lane wave handles exactly one edge: index loads are
// wave-uniform (broadcast), gather + atomic are 256B coalesced.

__global__ void scatter_kernel(const int* __restrict__ src, const int* __restrict__ dst,
                               const float* __restrict__ g, float* __restrict__ h) {
    int idx = blockIdx.x * blockDim.x + threadIdx.x;
    if (idx >= N_EDGES * HID) return;
    int e = idx >> 6, c = idx & 63;
    int s = src[e], d = dst[e];
    atomicAdd(&h[d * HID + c], g[s * HID + c]);
}

// ---------------- mid layer: hv = relu(dinv*h_raw + b_prev); g = dinv*(hv @ W); h = g ----------------
// One 64-lane wave per node; W staged in LDS; hv broadcast via shfl.

__global__ void mid_layer_kernel(const float* __restrict__ h_raw, const float* __restrict__ bprev,
                                 const float* __restrict__ W, const float* __restrict__ dinv,
                                 float* __restrict__ g, float* __restrict__ h) {
    __shared__ float Wl[HID * HID];
    for (int i = threadIdx.x; i < HID * HID; i += blockDim.x) Wl[i] = W[i];
    __syncthreads();
    int lane = threadIdx.x & 63;
    int wid = threadIdx.x >> 6;
    int n = blockIdx.x * (blockDim.x >> 6) + wid;
    if (n >= N_NODES) return;
    float di = dinv[n];
    float hv = fmaxf(di * h_raw[n * HID + lane] + bprev[lane], 0.0f);
    float acc = 0.0f;
#pragma unroll
    for (int k = 0; k < HID; ++k) {
        float hk = __shfl(hv, k, 64);
        acc = fmaf(hk, Wl[k * HID + lane], acc);
    }
    float v = di * acc;
    g[n * HID + lane] = v;
    h[n * HID + lane] = v;
}

// ---------------- MLP head ----------------
// hv = relu(dinv*h_raw + b3); m = relu(hv @ Wm1 + bm1); out = sigmoid(m @ Wm2 + bm2)

__global__ void mlp_kernel(const float* __restrict__ h_raw, const float* __restrict__ b3,
                           const float* __restrict__ Wm1, const float* __restrict__ bm1,
                           const float* __restrict__ Wm2, const float* __restrict__ bm2,
                           const float* __restrict__ dinv, float* __restrict__ out) {
    __shared__ float Wl[HID * HID];
    for (int i = threadIdx.x; i < HID * HID; i += blockDim.x) Wl[i] = Wm1[i];
    __syncthreads();
    int lane = threadIdx.x & 63;
    int wid = threadIdx.x >> 6;
    int n = blockIdx.x * (blockDim.x >> 6) + wid;
    if (n >= N_NODES) return;
    float di = dinv[n];
    float hv = fmaxf(di * h_raw[n * HID + lane] + b3[lane], 0.0f);
    float m = bm1[lane];
#pragma unroll
    for (int k = 0; k < HID; ++k) {
        float hk = __shfl(hv, k, 64);
        m = fmaf(hk, Wl[k * HID + lane], m);
    }
    m = fmaxf(m, 0.0f);
    float s = m * Wm2[lane];
#pragma unroll
    for (int off = 32; off > 0; off >>= 1) s += __shfl_down(s, off, 64);
    if (lane == 0) out[n] = 1.0f / (1.0f + expf(-(s + bm2[0])));
}

// ---------------- launch ----------------

extern "C" void kernel_launch(void* const* d_in, const int* in_sizes, int n_in,
                              void* d_out, int out_size, void* d_ws, size_t ws_size,
                              hipStream_t stream) {
    const float* x   = (const float*)d_in[0];
    const int*   ei  = (const int*)d_in[1];   // (2, E) row-major int32
    const float* W1  = (const float*)d_in[2];
    const float* b1  = (const float*)d_in[3];
    const float* W2  = (const float*)d_in[4];
    const float* b2  = (const float*)d_in[5];
    const float* W3  = (const float*)d_in[6];
    const float* b3  = (const float*)d_in[7];
    const float* Wm1 = (const float*)d_in[8];
    const float* bm1 = (const float*)d_in[9];
    const float* Wm2 = (const float*)d_in[10];
    const float* bm2 = (const float*)d_in[11];
    float* out = (float*)d_out;

    const int* src = ei;
    const int* dst = ei + N_EDGES;

    char* ws = (char*)d_ws;
    int*   deg  = (int*)(ws);                         // N ints
    float* dinv = (float*)(ws + 4ll * N_NODES);       // N floats
    float* g    = (float*)(ws + 8ll * N_NODES);       // N*64 floats
    float* h    = (float*)(ws + 8ll * N_NODES + 4ll * N_NODES * HID); // N*64 floats
    // total: 0.8 MB + 2 * 25.6 MB = 52 MB

    hipMemsetAsync(deg, 0, 4ll * N_NODES, stream);
    count_deg_kernel<<<(N_EDGES + 255) / 256, 256, 0, stream>>>(dst, deg);
    dinv_kernel<<<(N_NODES + 255) / 256, 256, 0, stream>>>(deg, dinv);

    // layer 1
    layer1_kernel<<<(N_NODES * HID + 255) / 256, 256, 0, stream>>>(x, W1, dinv, g, h);
    scatter_kernel<<<(N_EDGES * HID + 255) / 256, 256, 0, stream>>>(src, dst, g, h);

    // layer 2 (fuses layer-1 bias+relu)
    mid_layer_kernel<<<(N_NODES + 3) / 4, 256, 0, stream>>>(h, b1, W2, dinv, g, h);
    scatter_kernel<<<(N_EDGES * HID + 255) / 256, 256, 0, stream>>>(src, dst, g, h);

    // layer 3 (fuses layer-2 bias+relu)
    mid_layer_kernel<<<(N_NODES + 3) / 4, 256, 0, stream>>>(h, b2, W3, dinv, g, h);
    scatter_kernel<<<(N_EDGES * HID + 255) / 256, 256, 0, stream>>>(src, dst, g, h);

    // MLP head (fuses layer-3 bias+relu)
    mlp_kernel<<<(N_NODES + 3) / 4, 256, 0, stream>>>(h, b3, Wm1, bm1, Wm2, bm2, dinv, out);
}

// Round 2
// 878.464 us; speedup vs baseline: 1.7333x; 1.7333x over previous
//
#include <hip/hip_runtime.h>
#include <math.h>

#define N_NODES 100000
#define N_EDGES 1600000
#define HID 64

// ---------------- degree / normalization ----------------

__global__ void count_deg_kernel(const int* __restrict__ dst, int* __restrict__ deg) {
    int e = blockIdx.x * blockDim.x + threadIdx.x;
    if (e < N_EDGES) atomicAdd(&deg[dst[e]], 1);
}

__global__ void dinv_kernel(const int* __restrict__ deg, float* __restrict__ dinv) {
    int n = blockIdx.x * blockDim.x + threadIdx.x;
    if (n < N_NODES) dinv[n] = rsqrtf(1.0f + (float)deg[n]);
}

// ---------------- exclusive-scan rowptr (single block, 1024 threads) ----------------

__global__ void scan_kernel(const int* __restrict__ deg, int* __restrict__ rowptr) {
    __shared__ int wsum[17];
    __shared__ int carry_s;
    int tid = threadIdx.x;            // 1024 threads = 16 waves
    int lane = tid & 63, wid = tid >> 6;
    if (tid == 0) { carry_s = 0; rowptr[0] = 0; }
    __syncthreads();
    for (int base = 0; base < N_NODES; base += 1024) {
        int i = base + tid;
        int v = (i < N_NODES) ? deg[i] : 0;
        int x = v;  // inclusive scan within wave
#pragma unroll
        for (int off = 1; off < 64; off <<= 1) {
            int y = __shfl_up(x, off, 64);
            if (lane >= off) x += y;
        }
        if (lane == 63) wsum[wid] = x;
        __syncthreads();
        if (tid == 0) {
            int s = 0;
#pragma unroll
            for (int j = 0; j < 16; ++j) { int t = wsum[j]; wsum[j] = s; s += t; }
            wsum[16] = s;
        }
        __syncthreads();
        int c = carry_s;
        if (i < N_NODES) rowptr[i + 1] = c + wsum[wid] + x;
        __syncthreads();
        if (tid == 0) carry_s = c + wsum[16];
        __syncthreads();
    }
}

// ---------------- CSR fill: csr_src grouped by dst ----------------

__global__ void fill_csr_kernel(const int* __restrict__ src, const int* __restrict__ dst,
                                const int* __restrict__ rowptr, int* __restrict__ cursor,
                                int* __restrict__ csr_src) {
    int e = blockIdx.x * blockDim.x + threadIdx.x;
    if (e < N_EDGES) {
        int d = dst[e];
        int pos = rowptr[d] + atomicAdd(&cursor[d], 1);
        csr_src[pos] = src[e];
    }
}

// ---------------- layer 1: g = dinv * (x @ W1) ----------------

__global__ void layer1_kernel(const float* __restrict__ x, const float* __restrict__ W1,
                              const float* __restrict__ dinv, float* __restrict__ g) {
    int idx = blockIdx.x * blockDim.x + threadIdx.x;
    if (idx >= N_NODES * HID) return;
    int n = idx >> 6, c = idx & 63;
    float v = x[n * 3 + 0] * W1[0 * HID + c] + x[n * 3 + 1] * W1[1 * HID + c]
            + x[n * 3 + 2] * W1[2 * HID + c];
    g[idx] = v * dinv[n];
}

// ---------------- fused mid layer: pull-aggregate + bias/relu + 64x64 matmul ----------------
// One 64-lane wave per node (lane = feature). Neighbor indices fetched 64 at a
// time coalesced, then broadcast via shfl; each gather of g_in is a 256B
// coalesced wave read.

__global__ void agg_layer_kernel(const float* __restrict__ g_in, const int* __restrict__ rowptr,
                                 const int* __restrict__ csr, const float* __restrict__ dinv,
                                 const float* __restrict__ bprev, const float* __restrict__ W,
                                 float* __restrict__ g_out) {
    __shared__ float Wl[HID * HID];
    for (int i = threadIdx.x; i < HID * HID; i += blockDim.x) Wl[i] = W[i];
    __syncthreads();
    int lane = threadIdx.x & 63, wid = threadIdx.x >> 6;
    int n = blockIdx.x * (blockDim.x >> 6) + wid;
    if (n >= N_NODES) return;
    float acc = g_in[(long long)n * HID + lane];  // self-loop
    int beg = rowptr[n], end = rowptr[n + 1];
    for (int j0 = beg; j0 < end; j0 += 64) {
        int cnt = min(64, end - j0);
        int sv = (lane < cnt) ? csr[j0 + lane] : 0;
        for (int m = 0; m < cnt; ++m) {
            int s = __shfl(sv, m, 64);
            acc += g_in[(long long)s * HID + lane];
        }
    }
    float di = dinv[n];
    float hv = fmaxf(di * acc + bprev[lane], 0.0f);
    float r = 0.0f;
#pragma unroll
    for (int k = 0; k < HID; ++k) {
        float hk = __shfl(hv, k, 64);
        r = fmaf(hk, Wl[k * HID + lane], r);
    }
    g_out[(long long)n * HID + lane] = di * r;
}

// ---------------- final: pull-aggregate + relu + MLP head + sigmoid ----------------

__global__ void final_kernel(const float* __restrict__ g_in, const int* __restrict__ rowptr,
                             const int* __restrict__ csr, const float* __restrict__ dinv,
                             const float* __restrict__ b3, const float* __restrict__ Wm1,
                             const float* __restrict__ bm1, const float* __restrict__ Wm2,
                             const float* __restrict__ bm2, float* __restrict__ out) {
    __shared__ float Wl[HID * HID];
    for (int i = threadIdx.x; i < HID * HID; i += blockDim.x) Wl[i] = Wm1[i];
    __syncthreads();
    int lane = threadIdx.x & 63, wid = threadIdx.x >> 6;
    int n = blockIdx.x * (blockDim.x >> 6) + wid;
    if (n >= N_NODES) return;
    float acc = g_in[(long long)n * HID + lane];
    int beg = rowptr[n], end = rowptr[n + 1];
    for (int j0 = beg; j0 < end; j0 += 64) {
        int cnt = min(64, end - j0);
        int sv = (lane < cnt) ? csr[j0 + lane] : 0;
        for (int m = 0; m < cnt; ++m) {
            int s = __shfl(sv, m, 64);
            acc += g_in[(long long)s * HID + lane];
        }
    }
    float di = dinv[n];
    float hv = fmaxf(di * acc + b3[lane], 0.0f);
    float m = bm1[lane];
#pragma unroll
    for (int k = 0; k < HID; ++k) {
        float hk = __shfl(hv, k, 64);
        m = fmaf(hk, Wl[k * HID + lane], m);
    }
    m = fmaxf(m, 0.0f);
    float s = m * Wm2[lane];
#pragma unroll
    for (int off = 32; off > 0; off >>= 1) s += __shfl_down(s, off, 64);
    if (lane == 0) out[n] = 1.0f / (1.0f + expf(-(s + bm2[0])));
}

// ---------------- launch ----------------

extern "C" void kernel_launch(void* const* d_in, const int* in_sizes, int n_in,
                              void* d_out, int out_size, void* d_ws, size_t ws_size,
                              hipStream_t stream) {
    const float* x   = (const float*)d_in[0];
    const int*   ei  = (const int*)d_in[1];
    const float* W1  = (const float*)d_in[2];
    const float* b1  = (const float*)d_in[3];
    const float* W2  = (const float*)d_in[4];
    const float* b2  = (const float*)d_in[5];
    const float* W3  = (const float*)d_in[6];
    const float* b3  = (const float*)d_in[7];
    const float* Wm1 = (const float*)d_in[8];
    const float* bm1 = (const float*)d_in[9];
    const float* Wm2 = (const float*)d_in[10];
    const float* bm2 = (const float*)d_in[11];
    float* out = (float*)d_out;

    const int* src = ei;
    const int* dst = ei + N_EDGES;

    char* ws = (char*)d_ws;
    size_t off = 0;
    auto alloc = [&](size_t bytes) { size_t o = off; off = (off + bytes + 255) & ~(size_t)255; return (void*)(ws + o); };
    int*   deg    = (int*)alloc(4ll * N_NODES);        // doubles as cursor
    int*   rowptr = (int*)alloc(4ll * (N_NODES + 1));
    int*   csr    = (int*)alloc(4ll * N_EDGES);
    float* dinv   = (float*)alloc(4ll * N_NODES);
    float* gA     = (float*)alloc(4ll * N_NODES * HID);
    float* gB     = (float*)alloc(4ll * N_NODES * HID);
    (void)ws_size;

    // --- CSR build (per launch; same work every call) ---
    hipMemsetAsync(deg, 0, 4ll * N_NODES, stream);
    count_deg_kernel<<<(N_EDGES + 255) / 256, 256, 0, stream>>>(dst, deg);
    dinv_kernel<<<(N_NODES + 255) / 256, 256, 0, stream>>>(deg, dinv);
    scan_kernel<<<1, 1024, 0, stream>>>(deg, rowptr);
    hipMemsetAsync(deg, 0, 4ll * N_NODES, stream);  // reuse as cursor
    fill_csr_kernel<<<(N_EDGES + 255) / 256, 256, 0, stream>>>(src, dst, rowptr, deg, csr);

    // --- layers ---
    layer1_kernel<<<(N_NODES * HID + 255) / 256, 256, 0, stream>>>(x, W1, dinv, gA);
    agg_layer_kernel<<<(N_NODES + 3) / 4, 256, 0, stream>>>(gA, rowptr, csr, dinv, b1, W2, gB);
    agg_layer_kernel<<<(N_NODES + 3) / 4, 256, 0, stream>>>(gB, rowptr, csr, dinv, b2, W3, gA);
    final_kernel<<<(N_NODES + 3) / 4, 256, 0, stream>>>(gA, rowptr, csr, dinv, b3, Wm1, bm1, Wm2, bm2, out);
}

// Round 3
// 714.803 us; speedup vs baseline: 2.1301x; 1.2290x over previous
//
#include <hip/hip_runtime.h>
#include <math.h>

#define N_NODES 100000
#define N_EDGES 1600000
#define HID 64
#define SCAN_B 1024
#define NB ((N_NODES + SCAN_B - 1) / SCAN_B)   // 98 blocks

// ---------------- degree / normalization ----------------

__global__ void count_deg_kernel(const int* __restrict__ dst, int* __restrict__ deg) {
    int e = blockIdx.x * blockDim.x + threadIdx.x;
    if (e < N_EDGES) atomicAdd(&deg[dst[e]], 1);
}

__global__ void dinv_kernel(const int* __restrict__ deg, float* __restrict__ dinv) {
    int n = blockIdx.x * blockDim.x + threadIdx.x;
    if (n < N_NODES) dinv[n] = rsqrtf(1.0f + (float)deg[n]);
}

// ---------------- hierarchical scan: rowptr = exclusive_scan(deg) ----------------
// A) per-block inclusive scan -> rowptr[i+1], block total -> bsum[b]

__global__ void scan_block_kernel(const int* __restrict__ deg, int* __restrict__ rowptr,
                                  int* __restrict__ bsum) {
    __shared__ int wsum[16];
    int tid = threadIdx.x, lane = tid & 63, wid = tid >> 6;
    int i = blockIdx.x * SCAN_B + tid;
    int x = (i < N_NODES) ? deg[i] : 0;
#pragma unroll
    for (int off = 1; off < 64; off <<= 1) {
        int y = __shfl_up(x, off, 64);
        if (lane >= off) x += y;
    }
    if (lane == 63) wsum[wid] = x;
    __syncthreads();
    if (tid == 0) {
        int s = 0;
#pragma unroll
        for (int j = 0; j < 16; ++j) { int t = wsum[j]; wsum[j] = s; s += t; }
    }
    __syncthreads();
    int inc = wsum[wid] + x;
    if (i < N_NODES) rowptr[i + 1] = inc;
    if (tid == SCAN_B - 1) bsum[blockIdx.x] = inc;
}

// B) exclusive scan of the 98 block sums (single block, 128 threads)

__global__ void scan_bsum_kernel(int* __restrict__ bsum) {
    __shared__ int tmp[128];
    int t = threadIdx.x;
    tmp[t] = (t < NB) ? bsum[t] : 0;
    __syncthreads();
    for (int off = 1; off < 128; off <<= 1) {
        int v = (t >= off) ? tmp[t - off] : 0;
        __syncthreads();
        tmp[t] += v;
        __syncthreads();
    }
    if (t < NB) bsum[t] = (t == 0) ? 0 : tmp[t - 1];
}

// C) add block offsets

__global__ void add_off_kernel(int* __restrict__ rowptr, const int* __restrict__ bsum) {
    int i = blockIdx.x * SCAN_B + threadIdx.x;
    if (i == 0) rowptr[0] = 0;
    if (i < N_NODES) rowptr[i + 1] += bsum[blockIdx.x];
}

// ---------------- CSR fill ----------------

__global__ void fill_csr_kernel(const int* __restrict__ src, const int* __restrict__ dst,
                                const int* __restrict__ rowptr, int* __restrict__ cursor,
                                int* __restrict__ csr_src) {
    int e = blockIdx.x * blockDim.x + threadIdx.x;
    if (e < N_EDGES) {
        int d = dst[e];
        int pos = rowptr[d] + atomicAdd(&cursor[d], 1);
        csr_src[pos] = src[e];
    }
}

// ---------------- layer 1: g = dinv * (x @ W1) ----------------

__global__ void layer1_kernel(const float* __restrict__ x, const float* __restrict__ W1,
                              const float* __restrict__ dinv, float* __restrict__ g) {
    int idx = blockIdx.x * blockDim.x + threadIdx.x;
    if (idx >= N_NODES * HID) return;
    int n = idx >> 6, c = idx & 63;
    float v = x[n * 3 + 0] * W1[0 * HID + c] + x[n * 3 + 1] * W1[1 * HID + c]
            + x[n * 3 + 2] * W1[2 * HID + c];
    g[idx] = v * dinv[n];
}

// ---------------- gather with 8-way MLP ----------------
// 8 independent gathers issued before any accumulate -> 8 loads in flight/wave.

__device__ __forceinline__ float gather_neighbors(const float* __restrict__ g_in,
                                                  const int* __restrict__ csr,
                                                  int beg, int end, int lane, float acc) {
    for (int j0 = beg; j0 < end; j0 += 64) {
        int cnt = min(64, end - j0);
        int sv = (lane < cnt) ? csr[j0 + lane] : 0;
        int m = 0;
        for (; m + 8 <= cnt; m += 8) {
            int s0 = __shfl(sv, m + 0, 64), s1 = __shfl(sv, m + 1, 64);
            int s2 = __shfl(sv, m + 2, 64), s3 = __shfl(sv, m + 3, 64);
            int s4 = __shfl(sv, m + 4, 64), s5 = __shfl(sv, m + 5, 64);
            int s6 = __shfl(sv, m + 6, 64), s7 = __shfl(sv, m + 7, 64);
            float v0 = g_in[(long long)s0 * HID + lane];
            float v1 = g_in[(long long)s1 * HID + lane];
            float v2 = g_in[(long long)s2 * HID + lane];
            float v3 = g_in[(long long)s3 * HID + lane];
            float v4 = g_in[(long long)s4 * HID + lane];
            float v5 = g_in[(long long)s5 * HID + lane];
            float v6 = g_in[(long long)s6 * HID + lane];
            float v7 = g_in[(long long)s7 * HID + lane];
            acc += ((v0 + v1) + (v2 + v3)) + ((v4 + v5) + (v6 + v7));
        }
        for (; m < cnt; ++m) {
            int s = __shfl(sv, m, 64);
            acc += g_in[(long long)s * HID + lane];
        }
    }
    return acc;
}

// ---------------- fused mid layer ----------------

__global__ void agg_layer_kernel(const float* __restrict__ g_in, const int* __restrict__ rowptr,
                                 const int* __restrict__ csr, const float* __restrict__ dinv,
                                 const float* __restrict__ bprev, const float* __restrict__ W,
                                 float* __restrict__ g_out) {
    __shared__ float Wl[HID * HID];
    for (int i = threadIdx.x; i < HID * HID; i += blockDim.x) Wl[i] = W[i];
    __syncthreads();
    int lane = threadIdx.x & 63, wid = threadIdx.x >> 6;
    int n = blockIdx.x * (blockDim.x >> 6) + wid;
    if (n >= N_NODES) return;
    float acc = g_in[(long long)n * HID + lane];  // self-loop
    acc = gather_neighbors(g_in, csr, rowptr[n], rowptr[n + 1], lane, acc);
    float di = dinv[n];
    float hv = fmaxf(di * acc + bprev[lane], 0.0f);
    float r = 0.0f;
#pragma unroll
    for (int k = 0; k < HID; ++k) {
        float hk = __shfl(hv, k, 64);
        r = fmaf(hk, Wl[k * HID + lane], r);
    }
    g_out[(long long)n * HID + lane] = di * r;
}

// ---------------- final: aggregate + relu + MLP head + sigmoid ----------------

__global__ void final_kernel(const float* __restrict__ g_in, const int* __restrict__ rowptr,
                             const int* __restrict__ csr, const float* __restrict__ dinv,
                             const float* __restrict__ b3, const float* __restrict__ Wm1,
                             const float* __restrict__ bm1, const float* __restrict__ Wm2,
                             const float* __restrict__ bm2, float* __restrict__ out) {
    __shared__ float Wl[HID * HID];
    for (int i = threadIdx.x; i < HID * HID; i += blockDim.x) Wl[i] = Wm1[i];
    __syncthreads();
    int lane = threadIdx.x & 63, wid = threadIdx.x >> 6;
    int n = blockIdx.x * (blockDim.x >> 6) + wid;
    if (n >= N_NODES) return;
    float acc = g_in[(long long)n * HID + lane];
    acc = gather_neighbors(g_in, csr, rowptr[n], rowptr[n + 1], lane, acc);
    float di = dinv[n];
    float hv = fmaxf(di * acc + b3[lane], 0.0f);
    float m = bm1[lane];
#pragma unroll
    for (int k = 0; k < HID; ++k) {
        float hk = __shfl(hv, k, 64);
        m = fmaf(hk, Wl[k * HID + lane], m);
    }
    m = fmaxf(m, 0.0f);
    float s = m * Wm2[lane];
#pragma unroll
    for (int off = 32; off > 0; off >>= 1) s += __shfl_down(s, off, 64);
    if (lane == 0) out[n] = 1.0f / (1.0f + expf(-(s + bm2[0])));
}

// ---------------- launch ----------------

extern "C" void kernel_launch(void* const* d_in, const int* in_sizes, int n_in,
                              void* d_out, int out_size, void* d_ws, size_t ws_size,
                              hipStream_t stream) {
    const float* x   = (const float*)d_in[0];
    const int*   ei  = (const int*)d_in[1];
    const float* W1  = (const float*)d_in[2];
    const float* b1  = (const float*)d_in[3];
    const float* W2  = (const float*)d_in[4];
    const float* b2  = (const float*)d_in[5];
    const float* W3  = (const float*)d_in[6];
    const float* b3  = (const float*)d_in[7];
    const float* Wm1 = (const float*)d_in[8];
    const float* bm1 = (const float*)d_in[9];
    const float* Wm2 = (const float*)d_in[10];
    const float* bm2 = (const float*)d_in[11];
    float* out = (float*)d_out;

    const int* src = ei;
    const int* dst = ei + N_EDGES;

    char* ws = (char*)d_ws;
    size_t off = 0;
    auto alloc = [&](size_t bytes) { size_t o = off; off = (off + bytes + 255) & ~(size_t)255; return (void*)(ws + o); };
    int*   deg    = (int*)alloc(4ll * N_NODES);        // doubles as cursor
    int*   rowptr = (int*)alloc(4ll * (N_NODES + 1));
    int*   bsum   = (int*)alloc(4ll * NB);
    int*   csr    = (int*)alloc(4ll * N_EDGES);
    float* dinv   = (float*)alloc(4ll * N_NODES);
    float* gA     = (float*)alloc(4ll * N_NODES * HID);
    float* gB     = (float*)alloc(4ll * N_NODES * HID);
    (void)ws_size;

    // --- CSR build ---
    hipMemsetAsync(deg, 0, 4ll * N_NODES, stream);
    count_deg_kernel<<<(N_EDGES + 255) / 256, 256, 0, stream>>>(dst, deg);
    dinv_kernel<<<(N_NODES + 255) / 256, 256, 0, stream>>>(deg, dinv);
    scan_block_kernel<<<NB, SCAN_B, 0, stream>>>(deg, rowptr, bsum);
    scan_bsum_kernel<<<1, 128, 0, stream>>>(bsum);
    add_off_kernel<<<NB, SCAN_B, 0, stream>>>(rowptr, bsum);
    hipMemsetAsync(deg, 0, 4ll * N_NODES, stream);  // reuse as cursor
    fill_csr_kernel<<<(N_EDGES + 255) / 256, 256, 0, stream>>>(src, dst, rowptr, deg, csr);

    // --- layers ---
    layer1_kernel<<<(N_NODES * HID + 255) / 256, 256, 0, stream>>>(x, W1, dinv, gA);
    agg_layer_kernel<<<(N_NODES + 3) / 4, 256, 0, stream>>>(gA, rowptr, csr, dinv, b1, W2, gB);
    agg_layer_kernel<<<(N_NODES + 3) / 4, 256, 0, stream>>>(gB, rowptr, csr, dinv, b2, W3, gA);
    final_kernel<<<(N_NODES + 3) / 4, 256, 0, stream>>>(gA, rowptr, csr, dinv, b3, Wm1, bm1, Wm2, bm2, out);
}

// Round 4
// 639.317 us; speedup vs baseline: 2.3816x; 1.1181x over previous
//
#include <hip/hip_runtime.h>
#include <math.h>

#define N_NODES 100000
#define N_EDGES 1600000
#define HID 64
#define SCAN_B 1024
#define NB ((N_NODES + SCAN_B - 1) / SCAN_B)   // 98 blocks
#define NPW 16   // nodes per wave in fused layer kernels

// ---------------- degree / normalization ----------------

__global__ void count_deg_kernel(const int* __restrict__ dst, int* __restrict__ deg) {
    int e = blockIdx.x * blockDim.x + threadIdx.x;
    if (e < N_EDGES) atomicAdd(&deg[dst[e]], 1);
}

__global__ void dinv_kernel(const int* __restrict__ deg, float* __restrict__ dinv) {
    int n = blockIdx.x * blockDim.x + threadIdx.x;
    if (n < N_NODES) dinv[n] = rsqrtf(1.0f + (float)deg[n]);
}

// ---------------- hierarchical scan: rowptr = exclusive_scan(deg) ----------------

__global__ void scan_block_kernel(const int* __restrict__ deg, int* __restrict__ rowptr,
                                  int* __restrict__ bsum) {
    __shared__ int wsum[16];
    int tid = threadIdx.x, lane = tid & 63, wid = tid >> 6;
    int i = blockIdx.x * SCAN_B + tid;
    int x = (i < N_NODES) ? deg[i] : 0;
#pragma unroll
    for (int off = 1; off < 64; off <<= 1) {
        int y = __shfl_up(x, off, 64);
        if (lane >= off) x += y;
    }
    if (lane == 63) wsum[wid] = x;
    __syncthreads();
    if (tid == 0) {
        int s = 0;
#pragma unroll
        for (int j = 0; j < 16; ++j) { int t = wsum[j]; wsum[j] = s; s += t; }
    }
    __syncthreads();
    int inc = wsum[wid] + x;
    if (i < N_NODES) rowptr[i + 1] = inc;
    if (tid == SCAN_B - 1) bsum[blockIdx.x] = inc;
}

__global__ void scan_bsum_kernel(int* __restrict__ bsum) {
    __shared__ int tmp[128];
    int t = threadIdx.x;
    tmp[t] = (t < NB) ? bsum[t] : 0;
    __syncthreads();
    for (int off = 1; off < 128; off <<= 1) {
        int v = (t >= off) ? tmp[t - off] : 0;
        __syncthreads();
        tmp[t] += v;
        __syncthreads();
    }
    if (t < NB) bsum[t] = (t == 0) ? 0 : tmp[t - 1];
}

__global__ void add_off_kernel(int* __restrict__ rowptr, const int* __restrict__ bsum) {
    int i = blockIdx.x * SCAN_B + threadIdx.x;
    if (i == 0) rowptr[0] = 0;
    if (i < N_NODES) rowptr[i + 1] += bsum[blockIdx.x];
}

// ---------------- CSR fill ----------------

__global__ void fill_csr_kernel(const int* __restrict__ src, const int* __restrict__ dst,
                                const int* __restrict__ rowptr, int* __restrict__ cursor,
                                int* __restrict__ csr_src) {
    int e = blockIdx.x * blockDim.x + threadIdx.x;
    if (e < N_EDGES) {
        int d = dst[e];
        int pos = rowptr[d] + atomicAdd(&cursor[d], 1);
        csr_src[pos] = src[e];
    }
}

// ---------------- layer 1: g = dinv * (x @ W1) ----------------

__global__ void layer1_kernel(const float* __restrict__ x, const float* __restrict__ W1,
                              const float* __restrict__ dinv, float* __restrict__ g) {
    int idx = blockIdx.x * blockDim.x + threadIdx.x;
    if (idx >= N_NODES * HID) return;
    int n = idx >> 6, c = idx & 63;
    float v = x[n * 3 + 0] * W1[0 * HID + c] + x[n * 3 + 1] * W1[1 * HID + c]
            + x[n * 3 + 2] * W1[2 * HID + c];
    g[idx] = v * dinv[n];
}

// ---------------- gather: 8 independent loads in flight ----------------

__device__ __forceinline__ float gather_neighbors(const float* __restrict__ g_in,
                                                  const int* __restrict__ csr,
                                                  int beg, int end, int lane, float acc) {
    for (int j0 = beg; j0 < end; j0 += 64) {
        int cnt = min(64, end - j0);
        int sv = (lane < cnt) ? csr[j0 + lane] : 0;
        int m = 0;
        for (; m + 8 <= cnt; m += 8) {
            int s0 = __shfl(sv, m + 0, 64), s1 = __shfl(sv, m + 1, 64);
            int s2 = __shfl(sv, m + 2, 64), s3 = __shfl(sv, m + 3, 64);
            int s4 = __shfl(sv, m + 4, 64), s5 = __shfl(sv, m + 5, 64);
            int s6 = __shfl(sv, m + 6, 64), s7 = __shfl(sv, m + 7, 64);
            float v0 = g_in[s0 * HID + lane];
            float v1 = g_in[s1 * HID + lane];
            float v2 = g_in[s2 * HID + lane];
            float v3 = g_in[s3 * HID + lane];
            float v4 = g_in[s4 * HID + lane];
            float v5 = g_in[s5 * HID + lane];
            float v6 = g_in[s6 * HID + lane];
            float v7 = g_in[s7 * HID + lane];
            acc += ((v0 + v1) + (v2 + v3)) + ((v4 + v5) + (v6 + v7));
        }
        for (; m < cnt; ++m) {
            int s = __shfl(sv, m, 64);
            acc += g_in[s * HID + lane];
        }
    }
    return acc;
}

// ---------------- fused mid layer: W in VGPRs, hv broadcast via LDS b128 ----------------
// One wave processes NPW nodes. Lane j holds W[:, j] in 64 VGPRs (amortized over
// NPW nodes). Per node: gather (VMEM), hv -> 1 ds_write, 16 ds_read_b128
// same-address broadcasts + 64 FMA (4 accumulators). DS ops/node: 128 -> ~17.

__global__ __launch_bounds__(256, 4)
void agg_layer_kernel(const float* __restrict__ g_in, const int* __restrict__ rowptr,
                      const int* __restrict__ csr, const float* __restrict__ dinv,
                      const float* __restrict__ bprev, const float* __restrict__ W,
                      float* __restrict__ g_out) {
    __shared__ float hvbuf[4][HID];
    int lane = threadIdx.x & 63, wid = threadIdx.x >> 6;
    float Wreg[HID];
#pragma unroll
    for (int k = 0; k < HID; ++k) Wreg[k] = W[k * HID + lane];   // coalesced column load
    float bl = bprev[lane];
    float* hvp = &hvbuf[wid][0];
    const float4* hp4 = (const float4*)hvp;
    int wave = blockIdx.x * 4 + wid;
    int n0 = wave * NPW;
    for (int i = 0; i < NPW; ++i) {
        int n = n0 + i;
        if (n >= N_NODES) return;
        float acc = g_in[n * HID + lane];  // self-loop
        acc = gather_neighbors(g_in, csr, rowptr[n], rowptr[n + 1], lane, acc);
        float di = dinv[n];
        float hv = fmaxf(di * acc + bl, 0.0f);
        hvp[lane] = hv;
        float r0 = 0.f, r1 = 0.f, r2 = 0.f, r3 = 0.f;
#pragma unroll
        for (int kk = 0; kk < 16; ++kk) {
            float4 h4 = hp4[kk];   // same addr across lanes -> broadcast
            r0 = fmaf(h4.x, Wreg[4 * kk + 0], r0);
            r1 = fmaf(h4.y, Wreg[4 * kk + 1], r1);
            r2 = fmaf(h4.z, Wreg[4 * kk + 2], r2);
            r3 = fmaf(h4.w, Wreg[4 * kk + 3], r3);
        }
        g_out[n * HID + lane] = di * ((r0 + r1) + (r2 + r3));
    }
}

// ---------------- final: aggregate + relu + MLP head + sigmoid ----------------

__global__ __launch_bounds__(256, 4)
void final_kernel(const float* __restrict__ g_in, const int* __restrict__ rowptr,
                  const int* __restrict__ csr, const float* __restrict__ dinv,
                  const float* __restrict__ b3, const float* __restrict__ Wm1,
                  const float* __restrict__ bm1, const float* __restrict__ Wm2,
                  const float* __restrict__ bm2, float* __restrict__ out) {
    __shared__ float hvbuf[4][HID];
    int lane = threadIdx.x & 63, wid = threadIdx.x >> 6;
    float Wreg[HID];
#pragma unroll
    for (int k = 0; k < HID; ++k) Wreg[k] = Wm1[k * HID + lane];
    float bl = b3[lane];
    float bm1l = bm1[lane];
    float wm2l = Wm2[lane];
    float bm20 = bm2[0];
    float* hvp = &hvbuf[wid][0];
    const float4* hp4 = (const float4*)hvp;
    int wave = blockIdx.x * 4 + wid;
    int n0 = wave * NPW;
    for (int i = 0; i < NPW; ++i) {
        int n = n0 + i;
        if (n >= N_NODES) return;
        float acc = g_in[n * HID + lane];
        acc = gather_neighbors(g_in, csr, rowptr[n], rowptr[n + 1], lane, acc);
        float di = dinv[n];
        float hv = fmaxf(di * acc + bl, 0.0f);
        hvp[lane] = hv;
        float r0 = 0.f, r1 = 0.f, r2 = 0.f, r3 = 0.f;
#pragma unroll
        for (int kk = 0; kk < 16; ++kk) {
            float4 h4 = hp4[kk];
            r0 = fmaf(h4.x, Wreg[4 * kk + 0], r0);
            r1 = fmaf(h4.y, Wreg[4 * kk + 1], r1);
            r2 = fmaf(h4.z, Wreg[4 * kk + 2], r2);
            r3 = fmaf(h4.w, Wreg[4 * kk + 3], r3);
        }
        float m = fmaxf(((r0 + r1) + (r2 + r3)) + bm1l, 0.0f);
        float s = m * wm2l;
#pragma unroll
        for (int off = 32; off > 0; off >>= 1) s += __shfl_down(s, off, 64);
        if (lane == 0) out[n] = 1.0f / (1.0f + expf(-(s + bm20)));
    }
}

// ---------------- launch ----------------

extern "C" void kernel_launch(void* const* d_in, const int* in_sizes, int n_in,
                              void* d_out, int out_size, void* d_ws, size_t ws_size,
                              hipStream_t stream) {
    const float* x   = (const float*)d_in[0];
    const int*   ei  = (const int*)d_in[1];
    const float* W1  = (const float*)d_in[2];
    const float* b1  = (const float*)d_in[3];
    const float* W2  = (const float*)d_in[4];
    const float* b2  = (const float*)d_in[5];
    const float* W3  = (const float*)d_in[6];
    const float* b3  = (const float*)d_in[7];
    const float* Wm1 = (const float*)d_in[8];
    const float* bm1 = (const float*)d_in[9];
    const float* Wm2 = (const float*)d_in[10];
    const float* bm2 = (const float*)d_in[11];
    float* out = (float*)d_out;

    const int* src = ei;
    const int* dst = ei + N_EDGES;

    char* ws = (char*)d_ws;
    size_t off = 0;
    auto alloc = [&](size_t bytes) { size_t o = off; off = (off + bytes + 255) & ~(size_t)255; return (void*)(ws + o); };
    int*   deg    = (int*)alloc(4ll * N_NODES);        // doubles as cursor
    int*   rowptr = (int*)alloc(4ll * (N_NODES + 1));
    int*   bsum   = (int*)alloc(4ll * NB);
    int*   csr    = (int*)alloc(4ll * N_EDGES);
    float* dinv   = (float*)alloc(4ll * N_NODES);
    float* gA     = (float*)alloc(4ll * N_NODES * HID);
    float* gB     = (float*)alloc(4ll * N_NODES * HID);
    (void)ws_size;

    // --- CSR build ---
    hipMemsetAsync(deg, 0, 4ll * N_NODES, stream);
    count_deg_kernel<<<(N_EDGES + 255) / 256, 256, 0, stream>>>(dst, deg);
    dinv_kernel<<<(N_NODES + 255) / 256, 256, 0, stream>>>(deg, dinv);
    scan_block_kernel<<<NB, SCAN_B, 0, stream>>>(deg, rowptr, bsum);
    scan_bsum_kernel<<<1, 128, 0, stream>>>(bsum);
    add_off_kernel<<<NB, SCAN_B, 0, stream>>>(rowptr, bsum);
    hipMemsetAsync(deg, 0, 4ll * N_NODES, stream);  // reuse as cursor
    fill_csr_kernel<<<(N_EDGES + 255) / 256, 256, 0, stream>>>(src, dst, rowptr, deg, csr);

    // --- layers ---
    int nwaves = (N_NODES + NPW - 1) / NPW;
    int nblocks = (nwaves + 3) / 4;
    layer1_kernel<<<(N_NODES * HID + 255) / 256, 256, 0, stream>>>(x, W1, dinv, gA);
    agg_layer_kernel<<<nblocks, 256, 0, stream>>>(gA, rowptr, csr, dinv, b1, W2, gB);
    agg_layer_kernel<<<nblocks, 256, 0, stream>>>(gB, rowptr, csr, dinv, b2, W3, gA);
    final_kernel<<<nblocks, 256, 0, stream>>>(gA, rowptr, csr, dinv, b3, Wm1, bm1, Wm2, bm2, out);
}